// Round 6
// baseline (348.863 us; speedup 1.0000x reference)
//
#include <hip/hip_runtime.h>
#include <hip/hip_bf16.h>

#define NEGV (-1e9f)

typedef __attribute__((ext_vector_type(4))) float f32x4;
typedef __attribute__((ext_vector_type(8))) short short8;

#define MFMA_BF16(a, b, c) __builtin_amdgcn_mfma_f32_16x16x32_bf16((a), (b), (c), 0, 0, 0)

#define GLOAD_LDS16(gsrc, ldst)                                                        \
    __builtin_amdgcn_global_load_lds(                                                  \
        (const __attribute__((address_space(1))) unsigned int*)(gsrc),                 \
        (__attribute__((address_space(3))) unsigned int*)(ldst), 16, 0, 0)

#define GLOAD_LDS4(gsrc, ldst)                                                         \
    __builtin_amdgcn_global_load_lds(                                                  \
        (const __attribute__((address_space(1))) unsigned int*)(gsrc),                 \
        (__attribute__((address_space(3))) unsigned int*)(ldst), 4, 0, 0)

__device__ __forceinline__ unsigned short f2bf(float f) {
    union { float f; unsigned u; } v; v.f = f;
    return (unsigned short)((v.u + 0x7fffu + ((v.u >> 16) & 1u)) >> 16);
}

__device__ __forceinline__ float bf2f(unsigned short u) {
    return __uint_as_float((unsigned)u << 16);
}

// rotl via single v_alignbit_b32
#define ROTL(x, r) __builtin_amdgcn_alignbit((x), (x), 32 - (r))

// JAX threefry2x32 key=(0,42), partitionable mode — semantics verified round 1.
__device__ __forceinline__ unsigned tf_bits(unsigned idx) {
    const unsigned ks0 = 0u, ks1 = 42u, ks2 = 0x1BD11BDAu ^ 0u ^ 42u;
    unsigned x0 = ks0, x1 = idx + ks1;
#define TFR(r) { x0 += x1; x1 = ROTL(x1, (r)); x1 ^= x0; }
    TFR(13) TFR(15) TFR(26) TFR(6)   x0 += ks1; x1 += ks2 + 1u;
    TFR(17) TFR(29) TFR(16) TFR(24)  x0 += ks2; x1 += ks0 + 2u;
    TFR(13) TFR(15) TFR(26) TFR(6)   x0 += ks0; x1 += ks1 + 3u;
    TFR(17) TFR(29) TFR(16) TFR(24)  x0 += ks1; x1 += ks2 + 4u;
    TFR(13) TFR(15) TFR(26) TFR(6)   x0 += ks2; x1 += ks0 + 5u;
#undef TFR
    return x0 ^ x1;
}
// bern hit (u < 0.3f) as exact integer compare (verified round 5)
#define BERN_THRESH 1288490496u

// ---------------------------------------------------------------------------
// FUSED PREP + BERN. 3073 blocks:
//   odd bid  -> bern role (1536 blocks, grid-stride over flat causal task list,
//               4 independent threefry chains per wave-iter, scalar decode)
//   even bid -> idx = bid>>1:
//               [0,1024)    weight transpose tiles (4 matrices x 256 tiles)
//               [1024,1536) x f32->bf16 chunks
//               1536        mask canonicalize + bias concat
// ---------------------------------------------------------------------------
__global__ __launch_bounds__(256) void prep_bern_kernel(
    const float* __restrict__ x,
    const float* __restrict__ Wq, const float* __restrict__ Wk,
    const float* __restrict__ Wv, const float* __restrict__ Wo,
    const float* __restrict__ bq, const float* __restrict__ bk,
    const float* __restrict__ bv,
    const unsigned* __restrict__ mraw, const unsigned* __restrict__ dec,
    unsigned short* __restrict__ xb, unsigned short* __restrict__ wcat,
    unsigned short* __restrict__ wto, float* __restrict__ bcat,
    int* __restrict__ mcanon, unsigned long long* __restrict__ bw) {
    __shared__ float ts[64][68];         // transpose role (17.4 KB)
    __shared__ int fl_gt1, fl_nf, fl_odz;
    const int bid = blockIdx.x;
    const int t = threadIdx.x;

    if (bid & 1) {
        // ---------------- bern role ----------------
        const int dm = (dec[0] != 0u) ? 1 : 0;
        const int wgid = ((bid >> 1) << 2) + (t >> 6);  // 0..6143
        const int lane = t & 63;
        const int G = dm ? 139264 : 262144;             // 4-word groups
        for (int g = wgid; g < G; g += 6144) {
            int f = __builtin_amdgcn_readfirstlane(g) << 2;  // word index (scalar)
            int kw;
            if (dm) {
                kw = 0;
                while (f >= ((16 - kw) << 12)) { f -= (16 - kw) << 12; ++kw; }
            } else {
                kw = f >> 16; f &= 65535;
            }
            const int qoff = f >> 6;
            const int bh0 = f & 63;                     // 4-aligned
            const int q = (dm ? (kw << 6) : 0) + qoff;
            const unsigned base = ((unsigned)q << 10) + ((unsigned)kw << 6) + (unsigned)lane;
            const unsigned i0 = base + ((unsigned)(bh0 + 0) << 20);
            const unsigned i1 = base + ((unsigned)(bh0 + 1) << 20);
            const unsigned i2 = base + ((unsigned)(bh0 + 2) << 20);
            const unsigned i3 = base + ((unsigned)(bh0 + 3) << 20);
            // 4 independent chains -> ILP 4
            const unsigned r0 = tf_bits(i0), r1 = tf_bits(i1);
            const unsigned r2 = tf_bits(i2), r3 = tf_bits(i3);
            const unsigned long long w0 = __ballot(r0 < BERN_THRESH);
            const unsigned long long w1 = __ballot(r1 < BERN_THRESH);
            const unsigned long long w2 = __ballot(r2 < BERN_THRESH);
            const unsigned long long w3 = __ballot(r3 < BERN_THRESH);
            if (lane == 0) {
                const size_t rb = ((size_t)(((bh0 << 10) + q) << 4)) + (size_t)kw;
                bw[rb]         = w0;
                bw[rb + 16384] = w1;
                bw[rb + 32768] = w2;
                bw[rb + 49152] = w3;
            }
        }
    } else {
        const int idx = bid >> 1;
        if (idx < 1024) {
            // ---------------- weight transpose tile ----------------
            const int which = idx >> 8, tile = idx & 255;
            const float* W = (which == 0) ? Wq : (which == 1) ? Wk : (which == 2) ? Wv : Wo;
            unsigned short* WT = (which < 3) ? (wcat + (size_t)which * 1048576u) : wto;
            const int k0 = (tile >> 4) * 64, n0 = (tile & 15) * 64;
            const int r = t >> 4, c4 = (t & 15) * 4;
#pragma unroll
            for (int rr = 0; rr < 4; ++rr) {
                const int row = r + rr * 16;
                float4 v = *reinterpret_cast<const float4*>(&W[(size_t)(k0 + row) * 1024 + n0 + c4]);
                ts[row][c4 + 0] = v.x; ts[row][c4 + 1] = v.y;
                ts[row][c4 + 2] = v.z; ts[row][c4 + 3] = v.w;
            }
            __syncthreads();
#pragma unroll
            for (int rr = 0; rr < 4; ++rr) {
                const int n = r + rr * 16;
                ushort4 o;
                o.x = f2bf(ts[c4 + 0][n]); o.y = f2bf(ts[c4 + 1][n]);
                o.z = f2bf(ts[c4 + 2][n]); o.w = f2bf(ts[c4 + 3][n]);
                *reinterpret_cast<ushort4*>(&WT[(size_t)(n0 + n) * 1024 + k0 + c4]) = o;
            }
        } else if (idx < 1536) {
            // ---------------- x f32 -> bf16 chunk (8192 elems) ----------------
            const int c = idx - 1024;
            const float* src = x + (size_t)c * 8192;
            unsigned short* dst = xb + (size_t)c * 8192;
#pragma unroll
            for (int j = 0; j < 8; ++j) {
                const int off = j * 1024 + t * 4;
                float4 v = *reinterpret_cast<const float4*>(src + off);
                ushort4 o;
                o.x = f2bf(v.x); o.y = f2bf(v.y); o.z = f2bf(v.z); o.w = f2bf(v.w);
                *reinterpret_cast<ushort4*>(dst + off) = o;
            }
        } else {
            // ---------------- mask canonicalize + bias concat ----------------
            if (t == 0) { fl_gt1 = 0; fl_nf = 0; fl_odz = 0; }
            __syncthreads();
            for (int i = t; i < 1024; i += 256) {
                unsigned w0 = mraw[i];
                if (w0 > 1u) fl_gt1 = 1;
                if (w0 != 0u && w0 != 1u && w0 != 0x3f800000u) fl_nf = 1;
                if ((i & 1) && w0 != 0u) fl_odz = 1;
            }
            __syncthreads();
            int mode;  // 0=int32, 1=uint8, 2=float32, 3=int64
            if (!fl_gt1)      mode = fl_odz ? 0 : 3;
            else if (!fl_nf)  mode = 2;
            else              mode = 1;
            for (int i = t; i < 4096; i += 256) {
                int v;
                if (mode == 0)      v = (int)mraw[i];
                else if (mode == 1) v = ((const unsigned char*)mraw)[i] ? 1 : 0;
                else if (mode == 2) v = (mraw[i] != 0u) ? 1 : 0;
                else                v = (mraw[2 * i] != 0u) ? 1 : 0;
                mcanon[i] = v;
            }
            for (int i = t; i < 3072; i += 256)
                bcat[i] = (i < 1024) ? bq[i] : ((i < 2048) ? bk[i - 1024] : bv[i - 2048]);
        }
    }
}

// ---------------------------------------------------------------------------
// bf16 MFMA GEMM: C = relu(A[M,K] @ W + bias), W as BT[N][K] bf16.
// WMODE: 0=f32, 1=bf16, 2=bf16 split into 3 matrices of N=1024.
// ---------------------------------------------------------------------------
template<int MF, int WMODE>
__global__ __launch_bounds__(256) void gemm_bf16(
    const unsigned short* __restrict__ A, const unsigned short* __restrict__ BT,
    const float* __restrict__ bias, void* __restrict__ Cout,
    int M, int N, int K) {
    __shared__ unsigned short As[MF * 2048];
    __shared__ unsigned short Bs[8192];
    const int t = threadIdx.x;
    const int lane = t & 63, w = t >> 6;
    const int wr = w >> 1, wc = w & 1;
    const int lgrp = lane >> 4, l15 = lane & 15;
    const int m0 = blockIdx.y * (MF * 32), n0 = blockIdx.x * 128;
    const int srow = t >> 3;
    const int scol = ((t & 7) ^ (srow & 7)) << 3;
    const int rdsw = (l15 & 7) << 4;
    f32x4 acc[MF][4] = {};

    for (int k0 = 0; k0 < K; k0 += 64) {
#pragma unroll
        for (int s = 0; s < MF; ++s)
            GLOAD_LDS16(&A[(size_t)(m0 + s * 32 + srow) * K + (k0 + scol)], &As[s * 2048 + t * 8]);
#pragma unroll
        for (int s = 0; s < 4; ++s)
            GLOAD_LDS16(&BT[(size_t)(n0 + s * 32 + srow) * K + (k0 + scol)], &Bs[s * 2048 + t * 8]);
        __syncthreads();
#pragma unroll
        for (int kkh = 0; kkh < 2; ++kkh) {
            const int klb = (kkh * 32 + (lgrp << 3)) * 2;
            short8 af[MF], bf[4];
#pragma unroll
            for (int i = 0; i < MF; ++i)
                af[i] = *(const short8*)((const char*)As + (wr * (MF * 16) + i * 16 + l15) * 128 + (klb ^ rdsw));
#pragma unroll
            for (int i = 0; i < 4; ++i)
                bf[i] = *(const short8*)((const char*)Bs + (wc * 64 + i * 16 + l15) * 128 + (klb ^ rdsw));
            __builtin_amdgcn_s_setprio(1);
#pragma unroll
            for (int mf = 0; mf < MF; ++mf)
#pragma unroll
                for (int nf = 0; nf < 4; ++nf)
                    acc[mf][nf] = MFMA_BF16(af[mf], bf[nf], acc[mf][nf]);
            __builtin_amdgcn_s_setprio(0);
        }
        __syncthreads();
    }
#pragma unroll
    for (int nf = 0; nf < 4; ++nf) {
        const int n = n0 + wc * 64 + nf * 16 + l15;
        const float bv = bias[n];
#pragma unroll
        for (int mf = 0; mf < MF; ++mf) {
#pragma unroll
            for (int r = 0; r < 4; ++r) {
                const int m = m0 + wr * (MF * 16) + mf * 16 + (lgrp << 2) + r;
                float v = fmaxf(acc[mf][nf][r] + bv, 0.f);
                if (WMODE == 0) {
                    ((float*)Cout)[(size_t)m * N + n] = v;
                } else if (WMODE == 1) {
                    ((unsigned short*)Cout)[(size_t)m * N + n] = f2bf(v);
                } else {
                    const int which = n >> 10;
                    ((unsigned short*)Cout)[(size_t)which * 4194304u + (size_t)m * 1024 + (n & 1023)] = f2bf(v);
                }
            }
        }
    }
}

// ---------------------------------------------------------------------------
// V column means (degenerate softmax rows -> uniform over ALL keys).
// ---------------------------------------------------------------------------
__global__ __launch_bounds__(256) void vsum_part(const unsigned short* __restrict__ Vb,
                                                 float* __restrict__ part) {
    const int c = blockIdx.x, b = blockIdx.y, t = threadIdx.x;
    float a0 = 0, a1 = 0, a2 = 0, a3 = 0;
    const unsigned short* src = &Vb[((size_t)(b * 1024 + c * 64)) * 1024 + t * 4];
    for (int r = 0; r < 64; ++r) {
        ushort4 v = *(const ushort4*)(src + (size_t)r * 1024);
        a0 += bf2f(v.x); a1 += bf2f(v.y); a2 += bf2f(v.z); a3 += bf2f(v.w);
    }
    float4 o = {a0, a1, a2, a3};
    *(float4*)&part[(size_t)(b * 16 + c) * 1024 + t * 4] = o;
}

__global__ __launch_bounds__(256) void vsum_reduce(const float* __restrict__ part,
                                                   float* __restrict__ vmean) {
    const int b = blockIdx.x, t = threadIdx.x;
    float4 s = {0, 0, 0, 0};
    for (int c = 0; c < 16; ++c) {
        float4 v = *(const float4*)&part[(size_t)(b * 16 + c) * 1024 + t * 4];
        s.x += v.x; s.y += v.y; s.z += v.z; s.w += v.w;
    }
    const float sc = 1.0f / 1024.0f;
    float4 o = {s.x * sc, s.y * sc, s.z * sc, s.w * sc};
    *(float4*)&vmean[b * 1024 + t * 4] = o;
}

// ---------------------------------------------------------------------------
// Flash attention (round-4 structure + s_setprio around MFMA clusters).
// ---------------------------------------------------------------------------
__global__ __launch_bounds__(256) void attn_kernel(
    const unsigned short* __restrict__ Qb, const unsigned short* __restrict__ Kb,
    const unsigned short* __restrict__ Vb, const float* __restrict__ pos,
    const int* __restrict__ mcanon, const unsigned* __restrict__ dec,
    const unsigned long long* __restrict__ bern, const float* __restrict__ vmean,
    unsigned short* __restrict__ AO) {
    const int gx = blockIdx.x, h = blockIdx.y, b = blockIdx.z;
    const int t = threadIdx.x, lane = t & 63, w = t >> 6;
    const int lgrp = lane >> 4, l15 = lane & 15;

    __shared__ unsigned short Ks[4096];
    __shared__ unsigned short VT[4096];
    __shared__ float pos_s[4096];
    __shared__ int mask_s[64];

    const int dm = (dec[0] != 0u) ? 1 : 0;
    const int qt = (int)((0x765489AB3210CDEFull >> (((gx + 4 * b) & 15) << 2)) & 15);
    const int q0 = qt * 64;
    const int ntiles = dm ? (qt + 1) : 16;
    const int qi = q0 + w * 16 + l15;

    const size_t qg = ((size_t)(b * 1024 + qi)) * 1024 + h * 64 + (lgrp << 3);
    const short8 qb0 = *(const short8*)&Qb[qg];
    const short8 qb1 = *(const short8*)&Qb[qg + 32];
    const unsigned browbase = ((unsigned)((b * 16 + h) * 1024 + qi)) * 16u;

    float m = -3e38f, l = 0.f;
    f32x4 osc[4] = {};
    const int qor = w * 16 + (lgrp << 2);

    for (int kt = 0; kt < ntiles; ++kt) {
        const int kbase = kt * 64;
        {
            const int srow = t >> 3;
            const int scol = ((t & 7) ^ (srow & 7)) << 3;
            GLOAD_LDS16(&Kb[((size_t)(b * 1024 + kbase + srow)) * 1024 + h * 64 + scol],
                        &Ks[t * 8]);
            GLOAD_LDS16(&Kb[((size_t)(b * 1024 + kbase + 32 + srow)) * 1024 + h * 64 + scol],
                        &Ks[2048 + t * 8]);
        }
#pragma unroll
        for (int s = 0; s < 4; ++s) {
            const int row = w * 16 + s * 4 + (lane >> 4);
            const int scol = ((lane & 15) ^ (row & 15)) << 2;
            GLOAD_LDS16(&pos[((size_t)(b * 1024 + q0 + row)) * 1024 + kbase + scol],
                        &pos_s[w * 1024 + s * 256 + lane * 4]);
        }
        if (w == 0) GLOAD_LDS4(&mcanon[b * 1024 + kbase + lane], &mask_s[lane]);
        const unsigned long long bwv = bern[browbase + kt];
        {
            const int p = t >> 3;
            const int dblk = (t & 7) << 3;
            const unsigned short* vs = &Vb[((size_t)(b * 1024 + kbase + 2 * p)) * 1024 + h * 64 + dblk];
            short8 v0 = *(const short8*)vs;
            short8 v1 = *(const short8*)(vs + 1024);
#pragma unroll
            for (int j = 0; j < 8; ++j) {
                const int d = dblk + j;
                const int sw = (d & 7) ^ ((d >> 3) & 7);
                unsigned word = (unsigned)(unsigned short)v0[j] |
                                ((unsigned)(unsigned short)v1[j] << 16);
                *(unsigned*)((char*)VT + d * 128 + ((((2 * p) >> 3) ^ sw) << 4) +
                             (((2 * p) & 7) << 1)) = word;
            }
        }
        __syncthreads();  // A: staging visible

        f32x4 sacc[4] = {};
        __builtin_amdgcn_s_setprio(1);
#pragma unroll
        for (int kkh = 0; kkh < 2; ++kkh) {
            const int klb = (kkh * 32 + (lgrp << 3)) * 2;
            const short8 qf = kkh ? qb1 : qb0;
#pragma unroll
            for (int f = 0; f < 4; ++f) {
                short8 kf = *(const short8*)((const char*)Ks + (f * 16 + l15) * 128 +
                                             (klb ^ ((l15 & 7) << 4)));
                sacc[f] = MFMA_BF16(kf, qf, sacc[f]);
            }
        }
        __builtin_amdgcn_s_setprio(0);

        float p16[4][4];
        float tmax = -3e38f;
#pragma unroll
        for (int f = 0; f < 4; ++f) {
            const f32x4 posq = *(const f32x4*)&pos_s[(w * 16 + l15) * 64 +
                                                     (((f * 4 + lgrp) ^ l15) << 2)];
            const int4 mq = *(const int4*)&mask_s[f * 16 + (lgrp << 2)];
            const int mqa[4] = {mq.x, mq.y, mq.z, mq.w};
            const unsigned nib = (unsigned)(bwv >> (f * 16 + (lgrp << 2))) & 0xFu;
#pragma unroll
            for (int r = 0; r < 4; ++r) {
                const int ki = kbase + f * 16 + (lgrp << 2) + r;
                float lg = NEGV;
                const bool live = (mqa[r] == 0) && !(dm && (ki > qi));
                if (live) {
                    float sc = fmaf(sacc[f][r], 0.125f, posq[r]);
                    sc += ((nib >> r) & 1u) ? NEGV : 0.f;
                    lg = sc;
                }
                p16[f][r] = lg;
                tmax = fmaxf(tmax, lg);
            }
        }
        tmax = fmaxf(tmax, __shfl_xor(tmax, 16, 64));
        tmax = fmaxf(tmax, __shfl_xor(tmax, 32, 64));
        const float mn = fmaxf(m, tmax);
        const float fac = __expf(m - mn);

        float psum = 0.f;
        unsigned pk[4][2];
#pragma unroll
        for (int f = 0; f < 4; ++f) {
#pragma unroll
            for (int rr = 0; rr < 2; ++rr) {
                float pa = __expf(p16[f][2 * rr] - mn);
                float pb = __expf(p16[f][2 * rr + 1] - mn);
                psum += pa + pb;
                pk[f][rr] = (unsigned)f2bf(pa) | ((unsigned)f2bf(pb) << 16);
            }
        }
        psum += __shfl_xor(psum, 16, 64);
        psum += __shfl_xor(psum, 32, 64);
        l = l * fac + psum;
        m = mn;

#pragma unroll
        for (int r = 0; r < 4; ++r) {
            const float fr = __int_as_float(__builtin_amdgcn_ds_bpermute(
                (((lgrp << 2) + r) << 2), __float_as_int(fac)));
#pragma unroll
            for (int nf = 0; nf < 4; ++nf) osc[nf][r] *= fr;
        }

        {
            const int idx0 = ((((lgrp << 1) & 3) << 4) | l15) << 2;
            const int idx1 = (((((lgrp << 1) + 1) & 3) << 4) | l15) << 2;
            const bool hi = (lgrp >> 1) != 0;
#pragma unroll
            for (int kkh = 0; kkh < 2; ++kkh) {
                union { unsigned u[4]; short8 s; } pa;
#pragma unroll
                for (int s2 = 0; s2 < 4; ++s2) {
                    const int rr = s2 & 1;
                    const int idx = (s2 >> 1) ? idx1 : idx0;
                    const unsigned lo = (unsigned)__builtin_amdgcn_ds_bpermute(idx, (int)pk[kkh * 2][rr]);
                    const unsigned hw = (unsigned)__builtin_amdgcn_ds_bpermute(idx, (int)pk[kkh * 2 + 1][rr]);
                    pa.u[s2] = hi ? hw : lo;
                }
                __builtin_amdgcn_s_setprio(1);
#pragma unroll
                for (int nf = 0; nf < 4; ++nf) {
                    const int d = nf * 16 + l15;
                    const int sw = (d & 7) ^ ((d >> 3) & 7);
                    short8 vf = *(const short8*)((const char*)VT + d * 128 +
                                                 ((((kkh << 2) + lgrp) ^ sw) << 4));
                    osc[nf] = MFMA_BF16(pa.s, vf, osc[nf]);
                }
                __builtin_amdgcn_s_setprio(0);
            }
        }
        __syncthreads();  // B: LDS reads done
    }

#pragma unroll
    for (int r = 0; r < 4; ++r) {
        const int src = (((lgrp << 2) + r) << 2);
        const float lr = __int_as_float(__builtin_amdgcn_ds_bpermute(src, __float_as_int(l)));
        const float mr = __int_as_float(__builtin_amdgcn_ds_bpermute(src, __float_as_int(m)));
        const int qo = q0 + qor + r;
        const bool dgen = (mr == NEGV);
        const float inv = 1.0f / lr;
#pragma unroll
        for (int nf = 0; nf < 4; ++nf) {
            const int d = nf * 16 + l15;
            float v = dgen ? vmean[b * 1024 + h * 64 + d] : osc[nf][r] * inv;
            AO[((size_t)(b * 1024 + qo)) * 1024 + h * 64 + d] = f2bf(v);
        }
    }
}

// ---------------------------------------------------------------------------
extern "C" void kernel_launch(void* const* d_in, const int* in_sizes, int n_in,
                              void* d_out, int out_size, void* d_ws, size_t ws_size,
                              hipStream_t stream) {
    const float* x       = (const float*)d_in[0];
    const unsigned* mraw = (const unsigned*)d_in[1];
    const float* pos     = (const float*)d_in[2];
    const unsigned* dec  = (const unsigned*)d_in[3];
    const float* Wq = (const float*)d_in[4];  const float* bq = (const float*)d_in[5];
    const float* Wk = (const float*)d_in[6];  const float* bk = (const float*)d_in[7];
    const float* Wv = (const float*)d_in[8];  const float* bv = (const float*)d_in[9];
    const float* Wo = (const float*)d_in[10]; const float* bo = (const float*)d_in[11];
    float* out = (float*)d_out;

    char* ws = (char*)d_ws;
    unsigned short* xb   = (unsigned short*)(ws);                      // 8 MB (dead after QKV gemm)
    unsigned short* wcat = (unsigned short*)(ws + (8u << 20));         // 8 MB: Wq|Wk|Wv rows, then Wo
    unsigned short* wto  = wcat + 3u * 1024 * 1024;
    float* bcat          = (float*)(ws + (16u << 20));                 // 12 KB
    int* mcanon          = (int*)(ws + (16u << 20) + (64u << 10));     // 16 KB
    unsigned short* Qb   = (unsigned short*)(ws + (17u << 20));        // 3 x 8 MB
    unsigned short* Kb   = Qb + 4u * 1024 * 1024;
    unsigned short* Vb   = Qb + 8u * 1024 * 1024;
    unsigned short* AO   = (unsigned short*)(ws + (41u << 20));        // 8 MB
    unsigned long long* bern = (unsigned long long*)(ws + (49u << 20)); // 8 MB
    float* part  = (float*)(ws);               // overlaps xb (used after QKV gemm)
    float* vmean = (float*)(ws + (1u << 19));

    // Fused prep (x/W conversions, mask, bias) + bern precompute.
    prep_bern_kernel<<<3073, 256, 0, stream>>>(x, Wq, Wk, Wv, Wo, bq, bk, bv,
                                               mraw, dec, xb, wcat, wto, bcat,
                                               mcanon, bern);

    // QKV GEMM (N=3072, split-3 epilogue).
    gemm_bf16<4, 2><<<dim3(24, 32), 256, 0, stream>>>(xb, wcat, bcat, Qb, 4096, 3072, 1024);

    vsum_part<<<dim3(16, 4), 256, 0, stream>>>(Vb, part);
    vsum_reduce<<<4, 256, 0, stream>>>(part, vmean);

    attn_kernel<<<dim3(16, 16, 4), 256, 0, stream>>>(Qb, Kb, Vb, pos, mcanon, dec, bern, vmean, AO);

    gemm_bf16<2, 0><<<dim3(8, 64), 256, 0, stream>>>(AO, wto, bo, out, 4096, 1024, 1024);
}

// Round 7
// 319.982 us; speedup vs baseline: 1.0903x; 1.0903x over previous
//
#include <hip/hip_runtime.h>
#include <hip/hip_bf16.h>

#define NEGV (-1e9f)

typedef __attribute__((ext_vector_type(4))) float f32x4;
typedef __attribute__((ext_vector_type(8))) short short8;

#define MFMA_BF16(a, b, c) __builtin_amdgcn_mfma_f32_16x16x32_bf16((a), (b), (c), 0, 0, 0)

#define GLOAD_LDS16(gsrc, ldst)                                                        \
    __builtin_amdgcn_global_load_lds(                                                  \
        (const __attribute__((address_space(1))) unsigned int*)(gsrc),                 \
        (__attribute__((address_space(3))) unsigned int*)(ldst), 16, 0, 0)

#define GLOAD_LDS4(gsrc, ldst)                                                         \
    __builtin_amdgcn_global_load_lds(                                                  \
        (const __attribute__((address_space(1))) unsigned int*)(gsrc),                 \
        (__attribute__((address_space(3))) unsigned int*)(ldst), 4, 0, 0)

__device__ __forceinline__ unsigned short f2bf(float f) {
    union { float f; unsigned u; } v; v.f = f;
    return (unsigned short)((v.u + 0x7fffu + ((v.u >> 16) & 1u)) >> 16);
}

__device__ __forceinline__ float bf2f(unsigned short u) {
    return __uint_as_float((unsigned)u << 16);
}

// rotl via single v_alignbit_b32
#define ROTL(x, r) __builtin_amdgcn_alignbit((x), (x), 32 - (r))

// JAX threefry2x32 key=(0,42), partitionable mode — semantics verified round 1.
__device__ __forceinline__ unsigned tf_bits(unsigned idx) {
    const unsigned ks0 = 0u, ks1 = 42u, ks2 = 0x1BD11BDAu ^ 0u ^ 42u;
    unsigned x0 = ks0, x1 = idx + ks1;
#define TFR(r) { x0 += x1; x1 = ROTL(x1, (r)); x1 ^= x0; }
    TFR(13) TFR(15) TFR(26) TFR(6)   x0 += ks1; x1 += ks2 + 1u;
    TFR(17) TFR(29) TFR(16) TFR(24)  x0 += ks2; x1 += ks0 + 2u;
    TFR(13) TFR(15) TFR(26) TFR(6)   x0 += ks0; x1 += ks1 + 3u;
    TFR(17) TFR(29) TFR(16) TFR(24)  x0 += ks1; x1 += ks2 + 4u;
    TFR(13) TFR(15) TFR(26) TFR(6)   x0 += ks2; x1 += ks0 + 5u;
#undef TFR
    return x0 ^ x1;
}
// bern hit (u < 0.3f) as exact integer compare (verified rounds 5-6)
#define BERN_THRESH 1288490496u

// ---------------------------------------------------------------------------
// PREP (pure streaming): weight transposes, x f32->bf16, pos f32->bf16,
// mask canonicalize + bias concat. 2049 blocks.
// ---------------------------------------------------------------------------
__global__ __launch_bounds__(256) void prep_kernel(
    const float* __restrict__ x,
    const float* __restrict__ Wq, const float* __restrict__ Wk,
    const float* __restrict__ Wv, const float* __restrict__ Wo,
    const float* __restrict__ bq, const float* __restrict__ bk,
    const float* __restrict__ bv,
    const unsigned* __restrict__ mraw, const float* __restrict__ pos,
    unsigned short* __restrict__ xb, unsigned short* __restrict__ wcat,
    unsigned short* __restrict__ wto, float* __restrict__ bcat,
    int* __restrict__ mcanon, unsigned short* __restrict__ pos_bf) {
    __shared__ float ts[64][68];
    __shared__ int fl_gt1, fl_nf, fl_odz;
    const int bid = blockIdx.x;
    const int t = threadIdx.x;

    if (bid < 1024) {
        // ---------------- weight transpose tile ----------------
        const int which = bid >> 8, tile = bid & 255;
        const float* W = (which == 0) ? Wq : (which == 1) ? Wk : (which == 2) ? Wv : Wo;
        unsigned short* WT = (which < 3) ? (wcat + (size_t)which * 1048576u) : wto;
        const int k0 = (tile >> 4) * 64, n0 = (tile & 15) * 64;
        const int r = t >> 4, c4 = (t & 15) * 4;
#pragma unroll
        for (int rr = 0; rr < 4; ++rr) {
            const int row = r + rr * 16;
            float4 v = *reinterpret_cast<const float4*>(&W[(size_t)(k0 + row) * 1024 + n0 + c4]);
            ts[row][c4 + 0] = v.x; ts[row][c4 + 1] = v.y;
            ts[row][c4 + 2] = v.z; ts[row][c4 + 3] = v.w;
        }
        __syncthreads();
#pragma unroll
        for (int rr = 0; rr < 4; ++rr) {
            const int n = r + rr * 16;
            ushort4 o;
            o.x = f2bf(ts[c4 + 0][n]); o.y = f2bf(ts[c4 + 1][n]);
            o.z = f2bf(ts[c4 + 2][n]); o.w = f2bf(ts[c4 + 3][n]);
            *reinterpret_cast<ushort4*>(&WT[(size_t)(n0 + n) * 1024 + k0 + c4]) = o;
        }
    } else if (bid < 2048) {
        // ---------------- f32 -> bf16 chunks: x (512) then pos (512) ----------------
        const int c = bid - 1024;
        const float* src = (c < 512) ? (x + (size_t)c * 8192) : (pos + (size_t)(c - 512) * 8192);
        unsigned short* dst = (c < 512) ? (xb + (size_t)c * 8192) : (pos_bf + (size_t)(c - 512) * 8192);
#pragma unroll
        for (int j = 0; j < 8; ++j) {
            const int off = j * 1024 + t * 4;
            float4 v = *reinterpret_cast<const float4*>(src + off);
            ushort4 o;
            o.x = f2bf(v.x); o.y = f2bf(v.y); o.z = f2bf(v.z); o.w = f2bf(v.w);
            *reinterpret_cast<ushort4*>(dst + off) = o;
        }
    } else {
        // ---------------- mask canonicalize + bias concat ----------------
        if (t == 0) { fl_gt1 = 0; fl_nf = 0; fl_odz = 0; }
        __syncthreads();
        for (int i = t; i < 1024; i += 256) {
            unsigned w0 = mraw[i];
            if (w0 > 1u) fl_gt1 = 1;
            if (w0 != 0u && w0 != 1u && w0 != 0x3f800000u) fl_nf = 1;
            if ((i & 1) && w0 != 0u) fl_odz = 1;
        }
        __syncthreads();
        int mode;  // 0=int32, 1=uint8, 2=float32, 3=int64
        if (!fl_gt1)      mode = fl_odz ? 0 : 3;
        else if (!fl_nf)  mode = 2;
        else              mode = 1;
        for (int i = t; i < 4096; i += 256) {
            int v;
            if (mode == 0)      v = (int)mraw[i];
            else if (mode == 1) v = ((const unsigned char*)mraw)[i] ? 1 : 0;
            else if (mode == 2) v = (mraw[i] != 0u) ? 1 : 0;
            else                v = (mraw[2 * i] != 0u) ? 1 : 0;
            mcanon[i] = v;
        }
        for (int i = t; i < 3072; i += 256)
            bcat[i] = (i < 1024) ? bq[i] : ((i < 2048) ? bk[i - 1024] : bv[i - 2048]);
    }
}

// ---------------------------------------------------------------------------
// FUSED vsum_part (64 blocks, memory-bound) + BERN (512 blocks, VALU-bound).
// No LDS anywhere -> high co-residency. Bern: task = (bh, q-quad); 4 rows of a
// quad share nw=(q0>>6)+1 -> zero-branch uniform inner loop, 4 indep threefry
// chains (ILP-4). Stride-2048 task walk: per-wave word count 64 or 72 (±6%).
// ---------------------------------------------------------------------------
__global__ __launch_bounds__(256) void vsum_bern_kernel(
    const unsigned short* __restrict__ Vb, float* __restrict__ part,
    const unsigned* __restrict__ dec, unsigned long long* __restrict__ bw) {
    const int bid = blockIdx.x, t = threadIdx.x;
    if (bid < 64) {
        // ---------------- vsum_part role ----------------
        const int c = bid & 15, b = bid >> 4;
        float a0 = 0, a1 = 0, a2 = 0, a3 = 0;
        const unsigned short* src = &Vb[((size_t)(b * 1024 + c * 64)) * 1024 + t * 4];
        for (int r = 0; r < 64; ++r) {
            ushort4 v = *(const ushort4*)(src + (size_t)r * 1024);
            a0 += bf2f(v.x); a1 += bf2f(v.y); a2 += bf2f(v.z); a3 += bf2f(v.w);
        }
        float4 o = {a0, a1, a2, a3};
        *(float4*)&part[(size_t)(b * 16 + c) * 1024 + t * 4] = o;
    } else {
        // ---------------- bern role ----------------
        const int dm = (dec[0] != 0u) ? 1 : 0;
        const int wv = ((bid - 64) << 2) + (t >> 6);  // 0..2047
        const int lane = t & 63;
        for (int T = wv; T < 16384; T += 2048) {
            const int j = T >> 6, bh = T & 63;
            const int q0 = j << 2;
            const int nw = dm ? ((q0 >> 6) + 1) : 16;
            const unsigned rowb = ((unsigned)bh << 10) + (unsigned)q0;
            const unsigned base = (rowb << 10) + (unsigned)lane;
            const size_t ob = ((size_t)rowb << 4);
            for (int kw = 0; kw < nw; ++kw) {
                const unsigned kb2 = base + ((unsigned)kw << 6);
                const unsigned r0 = tf_bits(kb2);
                const unsigned r1 = tf_bits(kb2 + 1024u);
                const unsigned r2 = tf_bits(kb2 + 2048u);
                const unsigned r3 = tf_bits(kb2 + 3072u);
                const unsigned long long w0 = __ballot(r0 < BERN_THRESH);
                const unsigned long long w1 = __ballot(r1 < BERN_THRESH);
                const unsigned long long w2 = __ballot(r2 < BERN_THRESH);
                const unsigned long long w3 = __ballot(r3 < BERN_THRESH);
                if (lane == 0) {
                    bw[ob + kw]      = w0;
                    bw[ob + 16 + kw] = w1;
                    bw[ob + 32 + kw] = w2;
                    bw[ob + 48 + kw] = w3;
                }
            }
        }
    }
}

__global__ __launch_bounds__(256) void vsum_reduce(const float* __restrict__ part,
                                                   float* __restrict__ vmean) {
    const int b = blockIdx.x, t = threadIdx.x;
    float4 s = {0, 0, 0, 0};
    for (int c = 0; c < 16; ++c) {
        float4 v = *(const float4*)&part[(size_t)(b * 16 + c) * 1024 + t * 4];
        s.x += v.x; s.y += v.y; s.z += v.z; s.w += v.w;
    }
    const float sc = 1.0f / 1024.0f;
    float4 o = {s.x * sc, s.y * sc, s.z * sc, s.w * sc};
    *(float4*)&vmean[b * 1024 + t * 4] = o;
}

// ---------------------------------------------------------------------------
// bf16 MFMA GEMM: C = relu(A[M,K] @ W + bias), W as BT[N][K] bf16.
// WMODE: 0=f32, 1=bf16, 2=bf16 split into 3 matrices of N=1024.
// ---------------------------------------------------------------------------
template<int MF, int WMODE>
__global__ __launch_bounds__(256) void gemm_bf16(
    const unsigned short* __restrict__ A, const unsigned short* __restrict__ BT,
    const float* __restrict__ bias, void* __restrict__ Cout,
    int M, int N, int K) {
    __shared__ unsigned short As[MF * 2048];
    __shared__ unsigned short Bs[8192];
    const int t = threadIdx.x;
    const int lane = t & 63, w = t >> 6;
    const int wr = w >> 1, wc = w & 1;
    const int lgrp = lane >> 4, l15 = lane & 15;
    const int m0 = blockIdx.y * (MF * 32), n0 = blockIdx.x * 128;
    const int srow = t >> 3;
    const int scol = ((t & 7) ^ (srow & 7)) << 3;
    const int rdsw = (l15 & 7) << 4;
    f32x4 acc[MF][4] = {};

    for (int k0 = 0; k0 < K; k0 += 64) {
#pragma unroll
        for (int s = 0; s < MF; ++s)
            GLOAD_LDS16(&A[(size_t)(m0 + s * 32 + srow) * K + (k0 + scol)], &As[s * 2048 + t * 8]);
#pragma unroll
        for (int s = 0; s < 4; ++s)
            GLOAD_LDS16(&BT[(size_t)(n0 + s * 32 + srow) * K + (k0 + scol)], &Bs[s * 2048 + t * 8]);
        __syncthreads();
#pragma unroll
        for (int kkh = 0; kkh < 2; ++kkh) {
            const int klb = (kkh * 32 + (lgrp << 3)) * 2;
            short8 af[MF], bf[4];
#pragma unroll
            for (int i = 0; i < MF; ++i)
                af[i] = *(const short8*)((const char*)As + (wr * (MF * 16) + i * 16 + l15) * 128 + (klb ^ rdsw));
#pragma unroll
            for (int i = 0; i < 4; ++i)
                bf[i] = *(const short8*)((const char*)Bs + (wc * 64 + i * 16 + l15) * 128 + (klb ^ rdsw));
            __builtin_amdgcn_s_setprio(1);
#pragma unroll
            for (int mf = 0; mf < MF; ++mf)
#pragma unroll
                for (int nf = 0; nf < 4; ++nf)
                    acc[mf][nf] = MFMA_BF16(af[mf], bf[nf], acc[mf][nf]);
            __builtin_amdgcn_s_setprio(0);
        }
        __syncthreads();
    }
#pragma unroll
    for (int nf = 0; nf < 4; ++nf) {
        const int n = n0 + wc * 64 + nf * 16 + l15;
        const float bv = bias[n];
#pragma unroll
        for (int mf = 0; mf < MF; ++mf) {
#pragma unroll
            for (int r = 0; r < 4; ++r) {
                const int m = m0 + wr * (MF * 16) + mf * 16 + (lgrp << 2) + r;
                float v = fmaxf(acc[mf][nf][r] + bv, 0.f);
                if (WMODE == 0) {
                    ((float*)Cout)[(size_t)m * N + n] = v;
                } else if (WMODE == 1) {
                    ((unsigned short*)Cout)[(size_t)m * N + n] = f2bf(v);
                } else {
                    const int which = n >> 10;
                    ((unsigned short*)Cout)[(size_t)which * 4194304u + (size_t)m * 1024 + (n & 1023)] = f2bf(v);
                }
            }
        }
    }
}

// ---------------------------------------------------------------------------
// Flash attention: bf16 pos tiles (8 KB staged), LDS 24.6 KB -> 6 blocks/CU.
// ---------------------------------------------------------------------------
__global__ __launch_bounds__(256) void attn_kernel(
    const unsigned short* __restrict__ Qb, const unsigned short* __restrict__ Kb,
    const unsigned short* __restrict__ Vb, const unsigned short* __restrict__ pos_bf,
    const int* __restrict__ mcanon, const unsigned* __restrict__ dec,
    const unsigned long long* __restrict__ bern, const float* __restrict__ vmean,
    unsigned short* __restrict__ AO) {
    const int gx = blockIdx.x, h = blockIdx.y, b = blockIdx.z;
    const int t = threadIdx.x, lane = t & 63, w = t >> 6;
    const int lgrp = lane >> 4, l15 = lane & 15;

    __shared__ unsigned short Ks[4096];     // 64x64 bf16 [key][d], XOR-swizzled
    __shared__ unsigned short VT[4096];     // 64x64 bf16 [d][key], XOR-swizzled
    __shared__ unsigned short pos_s[4096];  // 64x64 bf16 [qloc][key], granule-swizzled
    __shared__ int mask_s[64];

    const int dm = (dec[0] != 0u) ? 1 : 0;
    const int qt = (int)((0x765489AB3210CDEFull >> (((gx + 4 * b) & 15) << 2)) & 15);
    const int q0 = qt * 64;
    const int ntiles = dm ? (qt + 1) : 16;
    const int qi = q0 + w * 16 + l15;

    const size_t qg = ((size_t)(b * 1024 + qi)) * 1024 + h * 64 + (lgrp << 3);
    const short8 qb0 = *(const short8*)&Qb[qg];
    const short8 qb1 = *(const short8*)&Qb[qg + 32];
    const unsigned browbase = ((unsigned)((b * 16 + h) * 1024 + qi)) * 16u;

    float m = -3e38f, l = 0.f;
    f32x4 osc[4] = {};
    const int qor = w * 16 + (lgrp << 2);

    for (int kt = 0; kt < ntiles; ++kt) {
        const int kbase = kt * 64;
        // ---- stage K ----
        {
            const int srow = t >> 3;
            const int scol = ((t & 7) ^ (srow & 7)) << 3;
            GLOAD_LDS16(&Kb[((size_t)(b * 1024 + kbase + srow)) * 1024 + h * 64 + scol],
                        &Ks[t * 8]);
            GLOAD_LDS16(&Kb[((size_t)(b * 1024 + kbase + 32 + srow)) * 1024 + h * 64 + scol],
                        &Ks[2048 + t * 8]);
        }
        // ---- stage pos (bf16, 2 gloads/wave, 16B-granule swizzle) ----
#pragma unroll
        for (int s = 0; s < 2; ++s) {
            const int row = w * 16 + s * 8 + (lane >> 3);
            const int gcol = ((lane & 7) ^ (row & 7)) << 3;
            GLOAD_LDS16(&pos_bf[((size_t)(b * 1024 + q0 + row)) * 1024 + kbase + gcol],
                        &pos_s[w * 1024 + s * 512 + lane * 8]);
        }
        if (w == 0) GLOAD_LDS4(&mcanon[b * 1024 + kbase + lane], &mask_s[lane]);
        const unsigned long long bwv = bern[browbase + kt];
        // ---- stage V^T (packed b32 writes) ----
        {
            const int p = t >> 3;
            const int dblk = (t & 7) << 3;
            const unsigned short* vs = &Vb[((size_t)(b * 1024 + kbase + 2 * p)) * 1024 + h * 64 + dblk];
            short8 v0 = *(const short8*)vs;
            short8 v1 = *(const short8*)(vs + 1024);
#pragma unroll
            for (int j = 0; j < 8; ++j) {
                const int d = dblk + j;
                const int sw = (d & 7) ^ ((d >> 3) & 7);
                unsigned word = (unsigned)(unsigned short)v0[j] |
                                ((unsigned)(unsigned short)v1[j] << 16);
                *(unsigned*)((char*)VT + d * 128 + ((((2 * p) >> 3) ^ sw) << 4) +
                             (((2 * p) & 7) << 1)) = word;
            }
        }
        __syncthreads();  // A: staging visible

        // ---- QK^T (swapped) ----
        f32x4 sacc[4] = {};
        __builtin_amdgcn_s_setprio(1);
#pragma unroll
        for (int kkh = 0; kkh < 2; ++kkh) {
            const int klb = (kkh * 32 + (lgrp << 3)) * 2;
            const short8 qf = kkh ? qb1 : qb0;
#pragma unroll
            for (int f = 0; f < 4; ++f) {
                short8 kf = *(const short8*)((const char*)Ks + (f * 16 + l15) * 128 +
                                             (klb ^ ((l15 & 7) << 4)));
                sacc[f] = MFMA_BF16(kf, qf, sacc[f]);
            }
        }
        __builtin_amdgcn_s_setprio(0);

        // ---- logits + row max ----
        const int prow = w * 16 + l15;
        float p16[4][4];
        float tmax = -3e38f;
#pragma unroll
        for (int f = 0; f < 4; ++f) {
            const int gsl = ((f << 1) + (lgrp >> 1)) ^ (prow & 7);
            const ushort4 pv = *(const ushort4*)((const char*)pos_s + prow * 128 +
                                                 (gsl << 4) + ((lgrp & 1) << 3));
            const float pr[4] = {bf2f(pv.x), bf2f(pv.y), bf2f(pv.z), bf2f(pv.w)};
            const int4 mq = *(const int4*)&mask_s[f * 16 + (lgrp << 2)];
            const int mqa[4] = {mq.x, mq.y, mq.z, mq.w};
            const unsigned nib = (unsigned)(bwv >> (f * 16 + (lgrp << 2))) & 0xFu;
#pragma unroll
            for (int r = 0; r < 4; ++r) {
                const int ki = kbase + f * 16 + (lgrp << 2) + r;
                float lg = NEGV;
                const bool live = (mqa[r] == 0) && !(dm && (ki > qi));
                if (live) {
                    float sc = fmaf(sacc[f][r], 0.125f, pr[r]);
                    sc += ((nib >> r) & 1u) ? NEGV : 0.f;
                    lg = sc;
                }
                p16[f][r] = lg;
                tmax = fmaxf(tmax, lg);
            }
        }
        tmax = fmaxf(tmax, __shfl_xor(tmax, 16, 64));
        tmax = fmaxf(tmax, __shfl_xor(tmax, 32, 64));
        const float mn = fmaxf(m, tmax);
        const float fac = __expf(m - mn);

        float psum = 0.f;
        unsigned pk[4][2];
#pragma unroll
        for (int f = 0; f < 4; ++f) {
#pragma unroll
            for (int rr = 0; rr < 2; ++rr) {
                float pa = __expf(p16[f][2 * rr] - mn);
                float pb = __expf(p16[f][2 * rr + 1] - mn);
                psum += pa + pb;
                pk[f][rr] = (unsigned)f2bf(pa) | ((unsigned)f2bf(pb) << 16);
            }
        }
        psum += __shfl_xor(psum, 16, 64);
        psum += __shfl_xor(psum, 32, 64);
        l = l * fac + psum;
        m = mn;

#pragma unroll
        for (int r = 0; r < 4; ++r) {
            const float fr = __int_as_float(__builtin_amdgcn_ds_bpermute(
                (((lgrp << 2) + r) << 2), __float_as_int(fac)));
#pragma unroll
            for (int nf = 0; nf < 4; ++nf) osc[nf][r] *= fr;
        }

        {
            const int idx0 = ((((lgrp << 1) & 3) << 4) | l15) << 2;
            const int idx1 = (((((lgrp << 1) + 1) & 3) << 4) | l15) << 2;
            const bool hi = (lgrp >> 1) != 0;
#pragma unroll
            for (int kkh = 0; kkh < 2; ++kkh) {
                union { unsigned u[4]; short8 s; } pa;
#pragma unroll
                for (int s2 = 0; s2 < 4; ++s2) {
                    const int rr = s2 & 1;
                    const int idx = (s2 >> 1) ? idx1 : idx0;
                    const unsigned lo = (unsigned)__builtin_amdgcn_ds_bpermute(idx, (int)pk[kkh * 2][rr]);
                    const unsigned hw = (unsigned)__builtin_amdgcn_ds_bpermute(idx, (int)pk[kkh * 2 + 1][rr]);
                    pa.u[s2] = hi ? hw : lo;
                }
                __builtin_amdgcn_s_setprio(1);
#pragma unroll
                for (int nf = 0; nf < 4; ++nf) {
                    const int d = nf * 16 + l15;
                    const int sw = (d & 7) ^ ((d >> 3) & 7);
                    short8 vf = *(const short8*)((const char*)VT + d * 128 +
                                                 ((((kkh << 2) + lgrp) ^ sw) << 4));
                    osc[nf] = MFMA_BF16(pa.s, vf, osc[nf]);
                }
                __builtin_amdgcn_s_setprio(0);
            }
        }
        __syncthreads();  // B: LDS reads done
    }

#pragma unroll
    for (int r = 0; r < 4; ++r) {
        const int src = (((lgrp << 2) + r) << 2);
        const float lr = __int_as_float(__builtin_amdgcn_ds_bpermute(src, __float_as_int(l)));
        const float mr = __int_as_float(__builtin_amdgcn_ds_bpermute(src, __float_as_int(m)));
        const int qo = q0 + qor + r;
        const bool dgen = (mr == NEGV);
        const float inv = 1.0f / lr;
#pragma unroll
        for (int nf = 0; nf < 4; ++nf) {
            const int d = nf * 16 + l15;
            float v = dgen ? vmean[b * 1024 + h * 64 + d] : osc[nf][r] * inv;
            AO[((size_t)(b * 1024 + qo)) * 1024 + h * 64 + d] = f2bf(v);
        }
    }
}

// ---------------------------------------------------------------------------
extern "C" void kernel_launch(void* const* d_in, const int* in_sizes, int n_in,
                              void* d_out, int out_size, void* d_ws, size_t ws_size,
                              hipStream_t stream) {
    const float* x       = (const float*)d_in[0];
    const unsigned* mraw = (const unsigned*)d_in[1];
    const float* pos     = (const float*)d_in[2];
    const unsigned* dec  = (const unsigned*)d_in[3];
    const float* Wq = (const float*)d_in[4];  const float* bq = (const float*)d_in[5];
    const float* Wk = (const float*)d_in[6];  const float* bk = (const float*)d_in[7];
    const float* Wv = (const float*)d_in[8];  const float* bv = (const float*)d_in[9];
    const float* Wo = (const float*)d_in[10]; const float* bo = (const float*)d_in[11];
    float* out = (float*)d_out;

    char* ws = (char*)d_ws;
    // Layout (57.4 MB total):
    //  [0,8M):    xb (bf16 x; dead after QKV gemm) -> part (vsum) -> AO (attn out)
    //  [8,16M):   wcat (6M) + wto (2M)
    //  [16M,+):   bcat 12K @ +0, mcanon 16K @ +64K, vmean 16K @ +128K
    //  [17,41M):  Qb, Kb, Vb
    //  [41,49M):  bern words
    //  [49,57.4M):pos_bf (bf16 pos)
    unsigned short* xb   = (unsigned short*)(ws);
    unsigned short* wcat = (unsigned short*)(ws + (8u << 20));
    unsigned short* wto  = wcat + 3u * 1024 * 1024;
    float* bcat          = (float*)(ws + (16u << 20));
    int* mcanon          = (int*)(ws + (16u << 20) + (64u << 10));
    float* vmean         = (float*)(ws + (16u << 20) + (128u << 10));
    unsigned short* Qb   = (unsigned short*)(ws + (17u << 20));
    unsigned short* Kb   = Qb + 4u * 1024 * 1024;
    unsigned short* Vb   = Qb + 8u * 1024 * 1024;
    unsigned long long* bern = (unsigned long long*)(ws + (41u << 20));
    unsigned short* pos_bf   = (unsigned short*)(ws + (49u << 20));
    float* part          = (float*)(ws);             // overlaps xb (used after QKV gemm)
    unsigned short* AO   = (unsigned short*)(ws);    // overlaps xb/part (used after vsum)

    prep_kernel<<<2049, 256, 0, stream>>>(x, Wq, Wk, Wv, Wo, bq, bk, bv,
                                          mraw, pos, xb, wcat, wto, bcat,
                                          mcanon, pos_bf);

    gemm_bf16<4, 2><<<dim3(24, 32), 256, 0, stream>>>(xb, wcat, bcat, Qb, 4096, 3072, 1024);

    vsum_bern_kernel<<<576, 256, 0, stream>>>(Vb, part, dec, bern);
    vsum_reduce<<<4, 256, 0, stream>>>(part, vmean);

    attn_kernel<<<dim3(16, 16, 4), 256, 0, stream>>>(Qb, Kb, Vb, pos_bf, mcanon, dec,
                                                     bern, vmean, AO);

    gemm_bf16<2, 0><<<dim3(8, 64), 256, 0, stream>>>(AO, wto, bo, out, 4096, 1024, 1024);
}